// Round 6
// baseline (129.155 us; speedup 1.0000x reference)
//
#include <hip/hip_runtime.h>
#include <hip/hip_cooperative_groups.h>

namespace cg = cooperative_groups;

#define NPOS 8500
#define BB 4
#define EMB 32
#define KP 16
#define MOM 528            /* S[16] + M[16][32] coefficients per batch */
#define NCHK 64            /* j-chunks per batch == tiles per batch */
#define TOUT 133           /* output positions per tile; 64*133 = 8512 */
#define NT 64              /* tiles per batch -> grid = 256 exactly */
#define STG 138            /* staged x idx [0,138): pos start-2 .. start+135 */
#define STR 142            /* LDS row stride (floats) */
#define THR 576            /* 9 waves: 8 ch-groups x 72 position lanes */
#define JPB 133            /* j's per chunk */
#define JPS 8              /* j's per half-wave subgroup (18 subgroups) */

__device__ __constant__ float c_invf[KP] = {
    1.f, 1.f, 0.5f, 1.f/6.f, 1.f/24.f, 1.f/120.f, 1.f/720.f, 1.f/5040.f,
    1.f/40320.f, 1.f/362880.f, 1.f/3628800.f, 1.f/39916800.f,
    1.f/479001600.f, 1.f/6227020800.f, 1.f/87178291200.f, 1.f/1307674368000.f};

__global__ __launch_bounds__(THR) void fused_kernel(
    const float* __restrict__ inten, const int* __restrict__ angle,
    const float* __restrict__ emb,
    const float* __restrict__ w1, const float* __restrict__ b1,
    const float* __restrict__ w2, const float* __restrict__ b2,
    float* __restrict__ part, float* __restrict__ out)
{
    __shared__ float w1t[3072];          // [c*3+d][o]
    __shared__ float w2t[3072];
    __shared__ float moms[MOM];
    __shared__ float b1s[EMB], b2s[EMB];
    __shared__ float pool[2 * EMB * STR]; // 9088 floats: xs+hs; overlaid by red[9][MOM] in phase 1
    float (*xs)[STR] = (float(*)[STR])pool;
    float (*hs)[STR] = (float(*)[STR])(pool + EMB * STR);
    float (*red)[MOM] = (float(*)[MOM])pool; // 9*528 = 4752 <= 9088

    const int t = threadIdx.x;
    const int b = blockIdx.x >> 6;
    const int chunk = blockIdx.x & 63;   // == tile index for phase 2
    const int e = t & 31;

    // ================= PHASE 1: partial moments (+ stage weights) =================
    // stage transposed weights into LDS (L2-resident after first block)
    for (int i = t; i < 3072; i += THR) {
        w1t[i] = w1[(i & 31) * 96 + (i >> 5)];
        w2t[i] = w2[(i & 31) * 96 + (i >> 5)];
    }
    if (t < EMB) { b1s[t] = b1[t]; b2s[t] = b2[t]; }

    // 18 half-wave subgroups of 32 lanes each take ~8 j's of this chunk
    const int wv = t >> 6;               // wave 0..8
    const int half = (t >> 5) & 1;
    const int sub = wv * 2 + half;       // 0..17
    const int jlo = chunk * JPB;
    const int jhi = min(jlo + JPB, NPOS);
    const int js = jlo + sub * JPS;
    const int je = min(js + JPS, jhi);

    float accM[KP], accS[KP];
#pragma unroll
    for (int k = 0; k < KP; ++k) { accM[k] = 0.f; accS[k] = 0.f; }

    {
        const float* ib = inten + b * NPOS;
        const int* ab = angle + b * NPOS;
        for (int j = js; j < je; ++j) {
            const float v = ib[j] * 0.01f;
            const int a = ab[j];
            const float ev = emb[a * EMB + e];   // 128B row per 32-lane group
            float p = 1.0f;
            accM[0] += ev;
            accS[0] += 1.0f;
#pragma unroll
            for (int k = 1; k < KP; ++k) {
                p *= v;
                accM[k] = fmaf(p, ev, accM[k]);
                accS[k] += p;
            }
        }
    }
    // fold the two halves of each wave (fixed order -> deterministic)
#pragma unroll
    for (int k = 0; k < KP; ++k) {
        accM[k] += __shfl_xor(accM[k], 32);
        accS[k] += __shfl_xor(accS[k], 32);
    }
    if (half == 0) {
#pragma unroll
        for (int k = 0; k < KP; ++k) red[wv][KP + k * EMB + e] = accM[k];
        if (e == 0) {
#pragma unroll
            for (int k = 0; k < KP; ++k) red[wv][k] = accS[k];
        }
    }
    __syncthreads();
    // block-level reduce of 9 wave-partials -> global part[b][coeff][chunk]
    for (int i = t; i < MOM; i += THR) {
        float s = 0.f;
#pragma unroll
        for (int u = 0; u < 9; ++u) s += red[u][i];
        part[((size_t)b * MOM + i) * NCHK + chunk] = s;
    }
    __threadfence();
    cg::this_grid().sync();

    // ================= PHASE 2: reduce -> x(Horner) -> conv1 -> conv2 =================
    const int start = chunk * TOUT;

    // reduce this batch's 64 chunk-partials: one coeff per thread, 16 x float4, 4-way ILP
    if (t < MOM) {
        const float4* pr = (const float4*)&part[((size_t)b * MOM + t) * NCHK];
        float4 a0 = pr[0], a1 = pr[1], a2 = pr[2], a3 = pr[3];
#pragma unroll
        for (int u = 4; u < 16; u += 4) {
            const float4 v0 = pr[u], v1 = pr[u + 1], v2 = pr[u + 2], v3 = pr[u + 3];
            a0.x += v0.x; a0.y += v0.y; a0.z += v0.z; a0.w += v0.w;
            a1.x += v1.x; a1.y += v1.y; a1.z += v1.z; a1.w += v1.w;
            a2.x += v2.x; a2.y += v2.y; a2.z += v2.z; a2.w += v2.w;
            a3.x += v3.x; a3.y += v3.y; a3.z += v3.z; a3.w += v3.w;
        }
        const float s = ((a0.x + a0.y) + (a0.z + a0.w)) + ((a1.x + a1.y) + (a1.z + a1.w))
                      + ((a2.x + a2.y) + (a2.z + a2.w)) + ((a3.x + a3.y) + (a3.z + a3.w));
        const int k = (t < KP) ? t : ((t - KP) >> 5);
        moms[t] = s * c_invf[k];
    }
    __syncthreads();

    // per-thread Horner coefficients (pre-scaled by 1/k!)
    float Mreg[KP], Sreg[KP];
#pragma unroll
    for (int k = 0; k < KP; ++k) {
        Mreg[k] = moms[KP + k * EMB + e];
        Sreg[k] = moms[k];
    }

    // ---- x-gen: xs[e][pos] = Horner_num(u)/Horner_den(u), zero outside [0,NPOS) ----
    for (int i = t; i < STG * EMB; i += THR) {   // THR % 32 == 0 -> lane e preserved
        const int pos = i >> 5;
        const int gp = start - 2 + pos;
        const bool valid = (gp >= 0) && (gp < NPOS);
        const float u = valid ? inten[b * NPOS + gp] * 0.01f : 0.f;
        float num = Mreg[KP - 1], den = Sreg[KP - 1];
#pragma unroll
        for (int k = KP - 2; k >= 0; --k) {
            num = fmaf(num, u, Mreg[k]);
            den = fmaf(den, u, Sreg[k]);
        }
        const float rd = valid ? __builtin_amdgcn_rcpf(den) : 0.f;
        xs[e][pos] = num * rd;
    }
    __syncthreads();

    const int g = t / 72;        // channel group (4 channels)
    const int lane = t - g * 72; // position lane (2 positions)
    const int o0 = g * 4;
    const int i0 = 2 * lane;

    // ---- conv1 + relu -> hs (h idx i0+1, i0+2 stored at i0, i0+1); need h 1..136 ----
    if (lane < 68) {
        float a[4][2];
#pragma unroll
        for (int oo = 0; oo < 4; ++oo) { a[oo][0] = b1s[o0 + oo]; a[oo][1] = b1s[o0 + oo]; }
#pragma unroll 4
        for (int c = 0; c < 32; ++c) {
            const float2 xa = *(const float2*)&xs[c][i0];
            const float2 xb = *(const float2*)&xs[c][i0 + 2];
            const float xv[4] = {xa.x, xa.y, xb.x, xb.y};
            const float4 W0 = *(const float4*)&w1t[(c * 3 + 0) * 32 + o0];
            const float4 W1 = *(const float4*)&w1t[(c * 3 + 1) * 32 + o0];
            const float4 W2 = *(const float4*)&w1t[(c * 3 + 2) * 32 + o0];
            const float w0a[4] = {W0.x, W0.y, W0.z, W0.w};
            const float w1a[4] = {W1.x, W1.y, W1.z, W1.w};
            const float w2a[4] = {W2.x, W2.y, W2.z, W2.w};
#pragma unroll
            for (int oo = 0; oo < 4; ++oo) {
                a[oo][0] = fmaf(w0a[oo], xv[0],
                           fmaf(w1a[oo], xv[1],
                           fmaf(w2a[oo], xv[2], a[oo][0])));
                a[oo][1] = fmaf(w0a[oo], xv[1],
                           fmaf(w1a[oo], xv[2],
                           fmaf(w2a[oo], xv[3], a[oo][1])));
            }
        }
        const int gp0 = start - 1 + i0;   // pos of h idx i0+1
        const bool v0 = (gp0 >= 0) && (gp0 < NPOS);
        const bool v1 = (gp0 + 1 >= 0) && (gp0 + 1 < NPOS);
#pragma unroll
        for (int oo = 0; oo < 4; ++oo) {
            float2 hv;
            hv.x = v0 ? fmaxf(a[oo][0], 0.f) : 0.f;
            hv.y = v1 ? fmaxf(a[oo][1], 0.f) : 0.f;
            *(float2*)&hs[o0 + oo][i0] = hv;
        }
    }
    __syncthreads();

    // ---- conv2 + residual + relu -> out (out idx i0+2, i0+3 -> pos start+i0, +1) ----
    if (lane < 67) {
        float a[4][2];
#pragma unroll
        for (int oo = 0; oo < 4; ++oo) { a[oo][0] = b2s[o0 + oo]; a[oo][1] = b2s[o0 + oo]; }
#pragma unroll 4
        for (int c = 0; c < 32; ++c) {
            const float2 ha = *(const float2*)&hs[c][i0];
            const float2 hb = *(const float2*)&hs[c][i0 + 2];
            const float hv[4] = {ha.x, ha.y, hb.x, hb.y};
            const float4 W0 = *(const float4*)&w2t[(c * 3 + 0) * 32 + o0];
            const float4 W1 = *(const float4*)&w2t[(c * 3 + 1) * 32 + o0];
            const float4 W2 = *(const float4*)&w2t[(c * 3 + 2) * 32 + o0];
            const float w0a[4] = {W0.x, W0.y, W0.z, W0.w};
            const float w1a[4] = {W1.x, W1.y, W1.z, W1.w};
            const float w2a[4] = {W2.x, W2.y, W2.z, W2.w};
#pragma unroll
            for (int oo = 0; oo < 4; ++oo) {
                a[oo][0] = fmaf(w0a[oo], hv[0],
                           fmaf(w1a[oo], hv[1],
                           fmaf(w2a[oo], hv[2], a[oo][0])));
                a[oo][1] = fmaf(w0a[oo], hv[1],
                           fmaf(w1a[oo], hv[2],
                           fmaf(w2a[oo], hv[3], a[oo][1])));
            }
        }
        const int p0 = start + i0;
        if (i0 < TOUT && p0 < NPOS) {
            const bool full = (i0 + 1 < TOUT) && (p0 + 1 < NPOS);
#pragma unroll
            for (int oo = 0; oo < 4; ++oo) {
                const float2 xr = *(const float2*)&xs[o0 + oo][i0 + 2];
                const float r0 = fmaxf(xr.x + a[oo][0], 0.f);
                const float r1 = fmaxf(xr.y + a[oo][1], 0.f);
                float* ob = out + (size_t)(b * EMB + o0 + oo) * NPOS + p0;
                if (full) *(float2*)ob = make_float2(r0, r1);
                else ob[0] = r0;
            }
        }
    }
}

extern "C" void kernel_launch(void* const* d_in, const int* in_sizes, int n_in,
                              void* d_out, int out_size, void* d_ws, size_t ws_size,
                              hipStream_t stream) {
    const float* inten = (const float*)d_in[0];
    const int* angle = (const int*)d_in[1];
    const float* emb = (const float*)d_in[2];
    const float* w1 = (const float*)d_in[3];
    const float* b1 = (const float*)d_in[4];
    const float* w2 = (const float*)d_in[5];
    const float* b2 = (const float*)d_in[6];
    float* out = (float*)d_out;
    float* part = (float*)d_ws;   // BB*528*64 floats = 540672 B

    void* kargs[] = {(void*)&inten, (void*)&angle, (void*)&emb,
                     (void*)&w1, (void*)&b1, (void*)&w2, (void*)&b2,
                     (void*)&part, (void*)&out};
    hipLaunchCooperativeKernel((const void*)fused_kernel, dim3(BB * NT), dim3(THR),
                               kargs, 0, stream);
}

// Round 7
// 38.078 us; speedup vs baseline: 3.3918x; 3.3918x over previous
//
#include <hip/hip_runtime.h>

#define NPOS 8500
#define BB 4
#define EMB 32
#define KP 16
#define MOM 528            /* S[16] + M[16][32] coefficients per batch */
#define NBLK 64            /* j-chunks per batch in k1 */
#define JPB 133            /* j's per chunk */
#define JPS 17             /* j's per 32-lane subgroup */
#define TOUT 126           /* output positions per tile */
#define NT 68              /* ceil(8500/126) -> grid 272 */
#define STG 130            /* staged x idx [0,130): pos start-2 .. start+127 */
#define STR 134            /* LDS row stride (floats) */
#define THR 512            /* 8 waves: 8 ch-groups x 64 position lanes */

__device__ __constant__ float c_invf[KP] = {
    1.f, 1.f, 0.5f, 1.f/6.f, 1.f/24.f, 1.f/120.f, 1.f/720.f, 1.f/5040.f,
    1.f/40320.f, 1.f/362880.f, 1.f/3628800.f, 1.f/39916800.f,
    1.f/479001600.f, 1.f/6227020800.f, 1.f/87178291200.f, 1.f/1307674368000.f};

// shallow power tree: p[1..15] = v^k, depth <= 6 mults
__device__ __forceinline__ void powtree(float v, float* p) {
    const float v2 = v * v;
    const float v4 = v2 * v2;
    const float v8 = v4 * v4;
    p[1] = v;        p[2] = v2;       p[3] = v2 * v;
    p[4] = v4;       p[5] = v4 * v;   p[6] = v4 * v2;
    p[7] = p[6] * v; p[8] = v8;       p[9] = v8 * v;
    p[10] = v8 * v2; p[11] = p[10] * v; p[12] = v8 * v4;
    p[13] = p[12] * v; p[14] = p[12] * v2; p[15] = p[14] * v;
}

// ---------------- kernel 1: partial moments (fixed order) + weight transpose ----------------
// part layout: part[(b*MOM + i)*NBLK + blk]  (blk contiguous -> float4 reduce)
__global__ __launch_bounds__(256) void moments_partial(
    const float* __restrict__ inten, const int* __restrict__ angle,
    const float* __restrict__ emb, float* __restrict__ part,
    const float* __restrict__ w1, const float* __restrict__ w2,
    float* __restrict__ wt)
{
    if (blockIdx.x == BB * NBLK) {
        for (int i = threadIdx.x; i < 3072; i += 256) {
            wt[i] = w1[(i & 31) * 96 + (i >> 5)];
            wt[3072 + i] = w2[(i & 31) * 96 + (i >> 5)];
        }
        return;
    }
    const int b = blockIdx.x >> 6;
    const int blk = blockIdx.x & 63;
    const int t = threadIdx.x;
    const int sub = t >> 5;                     // 8 subgroups of 32 lanes
    const int e = t & 31;                       // embed lane
    const int jlo = blk * JPB;
    const int jhi = min(jlo + JPB, NPOS);
    const int js = jlo + sub * JPS;
    const int je = min(js + JPS, jhi);

    float accM[KP], accS[KP];
#pragma unroll
    for (int k = 0; k < KP; ++k) { accM[k] = 0.f; accS[k] = 0.f; }

    const float* ib = inten + b * NPOS;
    const int* ab = angle + b * NPOS;
    int j = js;
    for (; j + 1 < je; j += 2) {                // 2 independent chains per iter
        const float va = ib[j] * 0.01f;
        const float vb = ib[j + 1] * 0.01f;
        const int aa = ab[j];
        const int abb = ab[j + 1];
        const float eva = emb[aa * EMB + e];
        const float evb = emb[abb * EMB + e];
        float pa[KP], pb[KP];
        powtree(va, pa);
        powtree(vb, pb);
        accM[0] += eva; accM[0] += evb;
        accS[0] += 2.0f;
#pragma unroll
        for (int k = 1; k < KP; ++k) {
            accM[k] = fmaf(pa[k], eva, accM[k]);
            accM[k] = fmaf(pb[k], evb, accM[k]);
            accS[k] += pa[k] + pb[k];
        }
    }
    if (j < je) {                               // tail
        const float v = ib[j] * 0.01f;
        const float ev = emb[ab[j] * EMB + e];
        float p[KP];
        powtree(v, p);
        accM[0] += ev;
        accS[0] += 1.0f;
#pragma unroll
        for (int k = 1; k < KP; ++k) {
            accM[k] = fmaf(p[k], ev, accM[k]);
            accS[k] += p[k];
        }
    }

    __shared__ float red[8][MOM];
#pragma unroll
    for (int k = 0; k < KP; ++k) red[sub][KP + k * EMB + e] = accM[k];
    if (e == 0) {
#pragma unroll
        for (int k = 0; k < KP; ++k) red[sub][k] = accS[k];
    }
    __syncthreads();
    for (int i = t; i < MOM; i += 256) {
        float s = 0.f;
#pragma unroll
        for (int u = 0; u < 8; ++u) s += red[u][i];
        part[((size_t)b * MOM + i) * NBLK + blk] = s;
    }
}

// ---------------- kernel 2: reduce + x(Horner) -> conv1+relu -> conv2+res+relu ----------------
__global__ __launch_bounds__(THR, 4) void main_kernel(
    const float* __restrict__ inten, const float* __restrict__ part,
    const float* __restrict__ wt, const float* __restrict__ b1,
    const float* __restrict__ b2, float* __restrict__ out)
{
    __shared__ float w1t[3072];     // [c*3+d][o]
    __shared__ float w2t[3072];
    __shared__ float moms[MOM];
    __shared__ float b1s[EMB], b2s[EMB];
    __shared__ float xs[EMB][STR];  // x idx 0..129 (pos = start-2+idx)
    __shared__ float hs[EMB][STR];  // h idx j stored at [j-1], j in 1..128

    const int t = threadIdx.x;
    const int b = blockIdx.x / NT;
    const int tile = blockIdx.x % NT;
    const int start = tile * TOUT;
    const int e = t & 31;

    // stage weights (coalesced float4 from pre-transposed wt)
    {
        const float4* src = (const float4*)wt;
        float4* d1 = (float4*)w1t;
        float4* d2 = (float4*)w2t;
        for (int i = t; i < 768; i += THR) { d1[i] = src[i]; d2[i] = src[768 + i]; }
        if (t < EMB) { b1s[t] = b1[t]; b2s[t] = b2[t]; }
    }
    // reduce this batch's partials: 16 x float4, 4-way ILP, fixed order
    for (int i = t; i < MOM; i += THR) {
        const float4* pr = (const float4*)&part[((size_t)b * MOM + i) * NBLK];
        float4 a0 = pr[0], a1 = pr[1], a2 = pr[2], a3 = pr[3];
#pragma unroll
        for (int u = 4; u < 16; u += 4) {
            const float4 v0 = pr[u], v1 = pr[u + 1], v2 = pr[u + 2], v3 = pr[u + 3];
            a0.x += v0.x; a0.y += v0.y; a0.z += v0.z; a0.w += v0.w;
            a1.x += v1.x; a1.y += v1.y; a1.z += v1.z; a1.w += v1.w;
            a2.x += v2.x; a2.y += v2.y; a2.z += v2.z; a2.w += v2.w;
            a3.x += v3.x; a3.y += v3.y; a3.z += v3.z; a3.w += v3.w;
        }
        const float s = ((a0.x + a0.y) + (a0.z + a0.w)) + ((a1.x + a1.y) + (a1.z + a1.w))
                      + ((a2.x + a2.y) + (a2.z + a2.w)) + ((a3.x + a3.y) + (a3.z + a3.w));
        const int k = (i < KP) ? i : ((i - KP) >> 5);
        moms[i] = s * c_invf[k];
    }
    __syncthreads();

    // per-thread Horner coefficients (pre-scaled by 1/k!)
    float Mreg[KP], Sreg[KP];
#pragma unroll
    for (int k = 0; k < KP; ++k) {
        Mreg[k] = moms[KP + k * EMB + e];
        Sreg[k] = moms[k];
    }

    // ---- x-gen: xs[e][pos] = Horner_num(u)/Horner_den(u), zero outside [0,NPOS) ----
    for (int i = t; i < STG * EMB; i += THR) {   // THR % 32 == 0 -> lane e preserved
        const int pos = i >> 5;
        const int gp = start - 2 + pos;
        const bool valid = (gp >= 0) && (gp < NPOS);
        const float u = valid ? inten[b * NPOS + gp] * 0.01f : 0.f;
        float num = Mreg[KP - 1], den = Sreg[KP - 1];
#pragma unroll
        for (int k = KP - 2; k >= 0; --k) {
            num = fmaf(num, u, Mreg[k]);
            den = fmaf(den, u, Sreg[k]);
        }
        const float rd = valid ? __builtin_amdgcn_rcpf(den) : 0.f;
        xs[e][pos] = num * rd;
    }
    __syncthreads();

    const int g = t >> 6;        // channel group (4 channels) == wave id
    const int lane = t & 63;     // position lane (2 positions)
    const int o0 = g * 4;
    const int i0 = 2 * lane;

    // ---- conv1 + relu -> hs (h idx i0+1, i0+2 stored at i0, i0+1); h 1..128 ----
    {
        float a[4][2];
#pragma unroll
        for (int oo = 0; oo < 4; ++oo) { a[oo][0] = b1s[o0 + oo]; a[oo][1] = b1s[o0 + oo]; }
#pragma unroll 4
        for (int c = 0; c < 32; ++c) {
            const float2 xa = *(const float2*)&xs[c][i0];
            const float2 xb = *(const float2*)&xs[c][i0 + 2];
            const float xv[4] = {xa.x, xa.y, xb.x, xb.y};
            const float4 W0 = *(const float4*)&w1t[(c * 3 + 0) * 32 + o0];  // wave-uniform
            const float4 W1 = *(const float4*)&w1t[(c * 3 + 1) * 32 + o0];
            const float4 W2 = *(const float4*)&w1t[(c * 3 + 2) * 32 + o0];
            const float w0a[4] = {W0.x, W0.y, W0.z, W0.w};
            const float w1a[4] = {W1.x, W1.y, W1.z, W1.w};
            const float w2a[4] = {W2.x, W2.y, W2.z, W2.w};
#pragma unroll
            for (int oo = 0; oo < 4; ++oo) {
                a[oo][0] = fmaf(w0a[oo], xv[0],
                           fmaf(w1a[oo], xv[1],
                           fmaf(w2a[oo], xv[2], a[oo][0])));
                a[oo][1] = fmaf(w0a[oo], xv[1],
                           fmaf(w1a[oo], xv[2],
                           fmaf(w2a[oo], xv[3], a[oo][1])));
            }
        }
        const int gp0 = start - 1 + i0;   // pos of h idx i0+1
        const bool v0 = (gp0 >= 0) && (gp0 < NPOS);
        const bool v1 = (gp0 + 1 >= 0) && (gp0 + 1 < NPOS);
#pragma unroll
        for (int oo = 0; oo < 4; ++oo) {
            float2 hv;
            hv.x = v0 ? fmaxf(a[oo][0], 0.f) : 0.f;
            hv.y = v1 ? fmaxf(a[oo][1], 0.f) : 0.f;
            *(float2*)&hs[o0 + oo][i0] = hv;
        }
    }
    __syncthreads();

    // ---- conv2 + residual + relu -> out (out idx i0+2, i0+3 -> pos start+i0, +1) ----
    if (lane < 63) {
        float a[4][2];
#pragma unroll
        for (int oo = 0; oo < 4; ++oo) { a[oo][0] = b2s[o0 + oo]; a[oo][1] = b2s[o0 + oo]; }
#pragma unroll 4
        for (int c = 0; c < 32; ++c) {
            const float2 ha = *(const float2*)&hs[c][i0];
            const float2 hb = *(const float2*)&hs[c][i0 + 2];
            const float hv[4] = {ha.x, ha.y, hb.x, hb.y};
            const float4 W0 = *(const float4*)&w2t[(c * 3 + 0) * 32 + o0];
            const float4 W1 = *(const float4*)&w2t[(c * 3 + 1) * 32 + o0];
            const float4 W2 = *(const float4*)&w2t[(c * 3 + 2) * 32 + o0];
            const float w0a[4] = {W0.x, W0.y, W0.z, W0.w};
            const float w1a[4] = {W1.x, W1.y, W1.z, W1.w};
            const float w2a[4] = {W2.x, W2.y, W2.z, W2.w};
#pragma unroll
            for (int oo = 0; oo < 4; ++oo) {
                a[oo][0] = fmaf(w0a[oo], hv[0],
                           fmaf(w1a[oo], hv[1],
                           fmaf(w2a[oo], hv[2], a[oo][0])));
                a[oo][1] = fmaf(w0a[oo], hv[1],
                           fmaf(w1a[oo], hv[2],
                           fmaf(w2a[oo], hv[3], a[oo][1])));
            }
        }
        const int p0 = start + i0;
        if (p0 < NPOS) {
            const bool full = (p0 + 1 < NPOS);
#pragma unroll
            for (int oo = 0; oo < 4; ++oo) {
                const float2 xr = *(const float2*)&xs[o0 + oo][i0 + 2];
                const float r0 = fmaxf(xr.x + a[oo][0], 0.f);
                const float r1 = fmaxf(xr.y + a[oo][1], 0.f);
                float* ob = out + (size_t)(b * EMB + o0 + oo) * NPOS + p0;
                if (full) *(float2*)ob = make_float2(r0, r1);
                else ob[0] = r0;
            }
        }
    }
}

extern "C" void kernel_launch(void* const* d_in, const int* in_sizes, int n_in,
                              void* d_out, int out_size, void* d_ws, size_t ws_size,
                              hipStream_t stream) {
    const float* inten = (const float*)d_in[0];
    const int* angle = (const int*)d_in[1];
    const float* emb = (const float*)d_in[2];
    const float* w1 = (const float*)d_in[3];
    const float* b1 = (const float*)d_in[4];
    const float* w2 = (const float*)d_in[5];
    const float* b2 = (const float*)d_in[6];
    float* out = (float*)d_out;

    float* part = (float*)d_ws;                                      // BB*528*64*4 = 540672 B
    float* wt = (float*)((char*)d_ws + (size_t)BB * MOM * NBLK * 4); // 6144 floats

    moments_partial<<<BB * NBLK + 1, 256, 0, stream>>>(inten, angle, emb, part, w1, w2, wt);
    main_kernel<<<BB * NT, THR, 0, stream>>>(inten, part, wt, b1, b2, out);
}

// Round 8
// 27.413 us; speedup vs baseline: 4.7114x; 1.3890x over previous
//
#include <hip/hip_runtime.h>

#define NPOS 8500
#define BB 4
#define EMB 32
#define KP 16
#define MOM 528            /* S[16] + M[16][32] coefficients per batch */
#define NBLK 64            /* j-chunks per batch in k1 */
#define JPB 133            /* j's per chunk */
#define JPS 17             /* j's per 32-lane subgroup */
#define TOUT 133           /* output positions per tile; 64*133 = 8512 */
#define NT 64              /* tiles per batch -> grid = 256 exactly */
#define STG 137            /* staged x idx [0,137): pos start-2 .. start+134 */
#define STR 138            /* LDS row stride (floats), rows 8B-aligned */
#define THR 576            /* 9 waves: 8 conv waves + 1 edge wave */

__device__ __constant__ float c_invf[KP] = {
    1.f, 1.f, 0.5f, 1.f/6.f, 1.f/24.f, 1.f/120.f, 1.f/720.f, 1.f/5040.f,
    1.f/40320.f, 1.f/362880.f, 1.f/3628800.f, 1.f/39916800.f,
    1.f/479001600.f, 1.f/6227020800.f, 1.f/87178291200.f, 1.f/1307674368000.f};

// ---------------- kernel 1: partial moments (fixed order) + weight transpose ----------------
// part layout: part[(b*MOM + i)*NBLK + blk]  (blk contiguous -> float4 reduce)
__global__ __launch_bounds__(256) void moments_partial(
    const float* __restrict__ inten, const int* __restrict__ angle,
    const float* __restrict__ emb, float* __restrict__ part,
    const float* __restrict__ w1, const float* __restrict__ w2,
    float* __restrict__ wt)
{
    if (blockIdx.x == BB * NBLK) {
        // transpose [o][c*3+d] -> [c*3+d][o] once
        for (int i = threadIdx.x; i < 3072; i += 256) {
            wt[i] = w1[(i & 31) * 96 + (i >> 5)];
            wt[3072 + i] = w2[(i & 31) * 96 + (i >> 5)];
        }
        return;
    }
    const int b = blockIdx.x >> 6;
    const int blk = blockIdx.x & 63;
    const int t = threadIdx.x;
    const int sub = t >> 5;                     // 8 subgroups of 32 lanes
    const int e = t & 31;                       // embed lane
    const int jlo = blk * JPB;
    const int jhi = min(jlo + JPB, NPOS);
    const int js = jlo + sub * JPS;
    const int je = min(js + JPS, jhi);

    float accM[KP], accS[KP];
#pragma unroll
    for (int k = 0; k < KP; ++k) { accM[k] = 0.f; accS[k] = 0.f; }

    const float* ib = inten + b * NPOS;
    const int* ab = angle + b * NPOS;
    for (int j = js; j < je; ++j) {
        const float v = ib[j] * 0.01f;
        const int a = ab[j];
        const float ev = emb[a * EMB + e];      // 128B row per 32-lane group
        float p = 1.0f;
        accM[0] += ev;
        accS[0] += 1.0f;
#pragma unroll
        for (int k = 1; k < KP; ++k) {
            p *= v;
            accM[k] = fmaf(p, ev, accM[k]);
            accS[k] += p;
        }
    }

    __shared__ float red[8][MOM];
#pragma unroll
    for (int k = 0; k < KP; ++k) red[sub][KP + k * EMB + e] = accM[k];
    if (e == 0) {
#pragma unroll
        for (int k = 0; k < KP; ++k) red[sub][k] = accS[k];
    }
    __syncthreads();
    for (int i = t; i < MOM; i += 256) {
        float s = 0.f;
#pragma unroll
        for (int u = 0; u < 8; ++u) s += red[u][i];
        part[((size_t)b * MOM + i) * NBLK + blk] = s;
    }
}

// ---------------- kernel 2: reduce + x(Horner) -> conv1+relu -> conv2+res+relu ----------------
// Weights come from GLOBAL wt via wave-uniform (scalar) loads -- zero LDS weight traffic.
__global__ __launch_bounds__(THR) void main_kernel(
    const float* __restrict__ inten, const float* __restrict__ part,
    const float* __restrict__ wt, const float* __restrict__ b1,
    const float* __restrict__ b2, float* __restrict__ out)
{
    __shared__ float moms[MOM];
    __shared__ float b1s[EMB], b2s[EMB];
    __shared__ float xs[EMB][STR];  // x idx 0..136 (pos = start-2+idx)
    __shared__ float hs[EMB][STR];  // h idx j stored at [j-1], j in 1..135

    const int t = threadIdx.x;
    const int b = blockIdx.x >> 6;      // NT = 64
    const int tile = blockIdx.x & 63;
    const int start = tile * TOUT;
    const int e = t & 31;

    if (t < EMB) { b1s[t] = b1[t]; b2s[t] = b2[t]; }
    // reduce this batch's partials: one coeff per thread, 16 x float4, 4-way ILP
    if (t < MOM) {
        const float4* pr = (const float4*)&part[((size_t)b * MOM + t) * NBLK];
        float4 a0 = pr[0], a1 = pr[1], a2 = pr[2], a3 = pr[3];
#pragma unroll
        for (int u = 4; u < 16; u += 4) {
            const float4 v0 = pr[u], v1 = pr[u + 1], v2 = pr[u + 2], v3 = pr[u + 3];
            a0.x += v0.x; a0.y += v0.y; a0.z += v0.z; a0.w += v0.w;
            a1.x += v1.x; a1.y += v1.y; a1.z += v1.z; a1.w += v1.w;
            a2.x += v2.x; a2.y += v2.y; a2.z += v2.z; a2.w += v2.w;
            a3.x += v3.x; a3.y += v3.y; a3.z += v3.z; a3.w += v3.w;
        }
        const float s = ((a0.x + a0.y) + (a0.z + a0.w)) + ((a1.x + a1.y) + (a1.z + a1.w))
                      + ((a2.x + a2.y) + (a2.z + a2.w)) + ((a3.x + a3.y) + (a3.z + a3.w));
        const int k = (t < KP) ? t : ((t - KP) >> 5);
        moms[t] = s * c_invf[k];
    }
    __syncthreads();

    // per-thread Horner coefficients (pre-scaled by 1/k!)
    float Mreg[KP], Sreg[KP];
#pragma unroll
    for (int k = 0; k < KP; ++k) {
        Mreg[k] = moms[KP + k * EMB + e];
        Sreg[k] = moms[k];
    }

    // ---- x-gen: xs[e][pos] = Horner_num(u)/Horner_den(u), zero outside [0,NPOS) ----
    for (int i = t; i < STG * EMB; i += THR) {   // THR % 32 == 0 -> lane e preserved
        const int pos = i >> 5;
        const int gp = start - 2 + pos;
        const bool valid = (gp >= 0) && (gp < NPOS);
        const float u = valid ? inten[b * NPOS + gp] * 0.01f : 0.f;
        float num = Mreg[KP - 1], den = Sreg[KP - 1];
#pragma unroll
        for (int k = KP - 2; k >= 0; --k) {
            num = fmaf(num, u, Mreg[k]);
            den = fmaf(den, u, Sreg[k]);
        }
        const float rd = valid ? __builtin_amdgcn_rcpf(den) : 0.f;
        xs[e][pos] = num * rd;
    }
    __syncthreads();

    const int wv = t >> 6;       // wave id 0..8
    const int lane = t & 63;

    // ---- conv1 + relu -> hs ----
    if (wv < 8) {
        // wave = one channel group of 4; weights wave-uniform -> scalar loads
        const int o0 = __builtin_amdgcn_readfirstlane(wv << 2);
        const int i0 = 2 * lane;             // h idx i0+1, i0+2 (1..128)
        float a[4][2];
#pragma unroll
        for (int oo = 0; oo < 4; ++oo) { a[oo][0] = b1s[o0 + oo]; a[oo][1] = b1s[o0 + oo]; }
        const float* wp = wt + o0;
#pragma unroll 4
        for (int c = 0; c < 32; ++c) {
            const float2 xa = *(const float2*)&xs[c][i0];
            const float2 xb = *(const float2*)&xs[c][i0 + 2];
            const float* wr = wp + c * 96;
#pragma unroll
            for (int oo = 0; oo < 4; ++oo) {
                const float wA = wr[oo], wB = wr[32 + oo], wC = wr[64 + oo];
                a[oo][0] = fmaf(wA, xa.x, fmaf(wB, xa.y, fmaf(wC, xb.x, a[oo][0])));
                a[oo][1] = fmaf(wA, xa.y, fmaf(wB, xb.x, fmaf(wC, xb.y, a[oo][1])));
            }
        }
        const int gp0 = start - 1 + i0;      // pos of h idx i0+1
        const bool v0 = (gp0 >= 0) && (gp0 < NPOS);
        const bool v1 = (gp0 + 1 >= 0) && (gp0 + 1 < NPOS);
#pragma unroll
        for (int oo = 0; oo < 4; ++oo) {
            float2 hv;
            hv.x = v0 ? fmaxf(a[oo][0], 0.f) : 0.f;
            hv.y = v1 ? fmaxf(a[oo][1], 0.f) : 0.f;
            *(float2*)&hs[o0 + oo][i0] = hv;
        }
    } else {
        // edge wave: h idx 129..135 for all 8 channel groups
        const int g2 = lane >> 3, p = lane & 7;
        if (p < 7) {
            const int o0e = g2 << 2;
            const int j = 129 + p;           // h idx
            float a[4];
#pragma unroll
            for (int oo = 0; oo < 4; ++oo) a[oo] = b1s[o0e + oo];
#pragma unroll 4
            for (int c = 0; c < 32; ++c) {
                const float x0 = xs[c][j - 1], x1 = xs[c][j], x2 = xs[c][j + 1];
                const float4 W0 = *(const float4*)&wt[(c * 3 + 0) * 32 + o0e];
                const float4 W1 = *(const float4*)&wt[(c * 3 + 1) * 32 + o0e];
                const float4 W2 = *(const float4*)&wt[(c * 3 + 2) * 32 + o0e];
                const float wa[4] = {W0.x, W0.y, W0.z, W0.w};
                const float wb[4] = {W1.x, W1.y, W1.z, W1.w};
                const float wc[4] = {W2.x, W2.y, W2.z, W2.w};
#pragma unroll
                for (int oo = 0; oo < 4; ++oo)
                    a[oo] = fmaf(wa[oo], x0, fmaf(wb[oo], x1, fmaf(wc[oo], x2, a[oo])));
            }
            const int gp = start - 2 + j;    // >= 127, only upper clamp needed
            const bool v = gp < NPOS;
#pragma unroll
            for (int oo = 0; oo < 4; ++oo)
                hs[o0e + oo][j - 1] = v ? fmaxf(a[oo], 0.f) : 0.f;
        }
    }
    __syncthreads();

    // ---- conv2 + residual + relu -> out ----
    if (wv < 8) {
        const int o0 = __builtin_amdgcn_readfirstlane(wv << 2);
        const int i0 = 2 * lane;             // out idx i0+2, i0+3 (2..129)
        float a[4][2];
#pragma unroll
        for (int oo = 0; oo < 4; ++oo) { a[oo][0] = b2s[o0 + oo]; a[oo][1] = b2s[o0 + oo]; }
        const float* wp = wt + 3072 + o0;
#pragma unroll 4
        for (int c = 0; c < 32; ++c) {
            const float2 ha = *(const float2*)&hs[c][i0];
            const float2 hb = *(const float2*)&hs[c][i0 + 2];
            const float* wr = wp + c * 96;
#pragma unroll
            for (int oo = 0; oo < 4; ++oo) {
                const float wA = wr[oo], wB = wr[32 + oo], wC = wr[64 + oo];
                a[oo][0] = fmaf(wA, ha.x, fmaf(wB, ha.y, fmaf(wC, hb.x, a[oo][0])));
                a[oo][1] = fmaf(wA, ha.y, fmaf(wB, hb.x, fmaf(wC, hb.y, a[oo][1])));
            }
        }
        const int p0 = start + i0;           // pos of out idx i0+2
        if (p0 < NPOS) {
            const bool full = (p0 + 1 < NPOS);
#pragma unroll
            for (int oo = 0; oo < 4; ++oo) {
                const float2 xr = *(const float2*)&xs[o0 + oo][i0 + 2];
                const float r0 = fmaxf(xr.x + a[oo][0], 0.f);
                const float r1 = fmaxf(xr.y + a[oo][1], 0.f);
                float* ob = out + (size_t)(b * EMB + o0 + oo) * NPOS + p0;
                if (full) *(float2*)ob = make_float2(r0, r1);
                else ob[0] = r0;
            }
        }
    } else {
        // edge wave: out idx 130..134 for all 8 channel groups
        const int g2 = lane >> 3, p = lane & 7;
        if (p < 5) {
            const int o0e = g2 << 2;
            const int q = 130 + p;           // out idx; h taps stored at [q-2],[q-1],[q]
            float a[4];
#pragma unroll
            for (int oo = 0; oo < 4; ++oo) a[oo] = b2s[o0e + oo];
#pragma unroll 4
            for (int c = 0; c < 32; ++c) {
                const float h0 = hs[c][q - 2], h1 = hs[c][q - 1], h2 = hs[c][q];
                const float4 W0 = *(const float4*)&wt[3072 + (c * 3 + 0) * 32 + o0e];
                const float4 W1 = *(const float4*)&wt[3072 + (c * 3 + 1) * 32 + o0e];
                const float4 W2 = *(const float4*)&wt[3072 + (c * 3 + 2) * 32 + o0e];
                const float wa[4] = {W0.x, W0.y, W0.z, W0.w};
                const float wb[4] = {W1.x, W1.y, W1.z, W1.w};
                const float wc[4] = {W2.x, W2.y, W2.z, W2.w};
#pragma unroll
                for (int oo = 0; oo < 4; ++oo)
                    a[oo] = fmaf(wa[oo], h0, fmaf(wb[oo], h1, fmaf(wc[oo], h2, a[oo])));
            }
            const int pos = start + q - 2;   // start+128+p
            if (pos < NPOS) {
#pragma unroll
                for (int oo = 0; oo < 4; ++oo) {
                    const float r = fmaxf(xs[o0e + oo][q] + a[oo], 0.f);
                    out[(size_t)(b * EMB + o0e + oo) * NPOS + pos] = r;
                }
            }
        }
    }
}

extern "C" void kernel_launch(void* const* d_in, const int* in_sizes, int n_in,
                              void* d_out, int out_size, void* d_ws, size_t ws_size,
                              hipStream_t stream) {
    const float* inten = (const float*)d_in[0];
    const int* angle = (const int*)d_in[1];
    const float* emb = (const float*)d_in[2];
    const float* w1 = (const float*)d_in[3];
    const float* b1 = (const float*)d_in[4];
    const float* w2 = (const float*)d_in[5];
    const float* b2 = (const float*)d_in[6];
    float* out = (float*)d_out;

    float* part = (float*)d_ws;                                      // BB*528*64*4 = 540672 B
    float* wt = (float*)((char*)d_ws + (size_t)BB * MOM * NBLK * 4); // 6144 floats

    moments_partial<<<BB * NBLK + 1, 256, 0, stream>>>(inten, angle, emb, part, w1, w2, wt);
    main_kernel<<<BB * NT, THR, 0, stream>>>(inten, part, wt, b1, b2, out);
}

// Round 9
// 26.900 us; speedup vs baseline: 4.8013x; 1.0191x over previous
//
#include <hip/hip_runtime.h>

#define NPOS 8500
#define BB 4
#define EMB 32
#define KP 16
#define MOM 528            /* S[16] + M[16][32] coefficients per batch */
#define NBLK 64            /* j-chunks per batch in k1 */
#define JPB 133            /* j's per chunk */
#define JPS 9              /* j's per 32-lane subgroup (16 subgroups) */
#define TOUT 133           /* output positions per tile; 64*133 = 8512 */
#define NT 64              /* tiles per batch -> grid = 256 exactly */
#define STG 137            /* staged x idx [0,137): pos start-2 .. start+134 */
#define STR 138            /* LDS row stride (floats), rows 8B-aligned */
#define THR 576            /* 9 waves: 8 conv waves + 1 edge wave */

__device__ __constant__ float c_invf[KP] = {
    1.f, 1.f, 0.5f, 1.f/6.f, 1.f/24.f, 1.f/120.f, 1.f/720.f, 1.f/5040.f,
    1.f/40320.f, 1.f/362880.f, 1.f/3628800.f, 1.f/39916800.f,
    1.f/479001600.f, 1.f/6227020800.f, 1.f/87178291200.f, 1.f/1307674368000.f};

// shallow power tree: p[1..15] = v^k, depth <= 4 mults
__device__ __forceinline__ void powtree(float v, float* p) {
    const float v2 = v * v;
    const float v4 = v2 * v2;
    const float v8 = v4 * v4;
    p[1] = v;          p[2] = v2;         p[3] = v2 * v;
    p[4] = v4;         p[5] = v4 * v;     p[6] = v4 * v2;
    p[7] = v4 * p[3];  p[8] = v8;         p[9] = v8 * v;
    p[10] = v8 * v2;   p[11] = v8 * p[3]; p[12] = v8 * v4;
    p[13] = v8 * p[5]; p[14] = v8 * p[6]; p[15] = v8 * p[7];
}

// ---------------- kernel 1: partial moments (fixed order), grid = 256 exactly ----------------
// part layout: part[(b*MOM + i)*NBLK + blk]  (blk contiguous -> float4 reduce in main)
__global__ __launch_bounds__(512) void moments_partial(
    const float* __restrict__ inten, const int* __restrict__ angle,
    const float* __restrict__ emb, float* __restrict__ part)
{
    const int b = blockIdx.x >> 6;
    const int blk = blockIdx.x & 63;
    const int t = threadIdx.x;
    const int sub = t >> 5;                     // 16 subgroups of 32 lanes
    const int e = t & 31;                       // embed lane
    const int jlo = blk * JPB;
    const int jhi = min(jlo + JPB, NPOS);
    const int js = jlo + sub * JPS;
    const int je = min(js + JPS, jhi);

    float accM[KP], accS[KP];
#pragma unroll
    for (int k = 0; k < KP; ++k) { accM[k] = 0.f; accS[k] = 0.f; }

    const float* ib = inten + b * NPOS;
    const int* ab = angle + b * NPOS;
    int j = js;
    for (; j + 1 < je; j += 2) {                // two independent power chains
        const float va = ib[j] * 0.01f;
        const float vb = ib[j + 1] * 0.01f;
        const float eva = emb[ab[j] * EMB + e];
        const float evb = emb[ab[j + 1] * EMB + e];
        float pa[KP], pb[KP];
        powtree(va, pa);
        powtree(vb, pb);
        accM[0] += eva + evb;
        accS[0] += 2.0f;
#pragma unroll
        for (int k = 1; k < KP; ++k) {
            accM[k] = fmaf(pa[k], eva, accM[k]);
            accM[k] = fmaf(pb[k], evb, accM[k]);
            accS[k] += pa[k] + pb[k];
        }
    }
    if (j < je) {
        const float v = ib[j] * 0.01f;
        const float ev = emb[ab[j] * EMB + e];
        float p[KP];
        powtree(v, p);
        accM[0] += ev;
        accS[0] += 1.0f;
#pragma unroll
        for (int k = 1; k < KP; ++k) {
            accM[k] = fmaf(p[k], ev, accM[k]);
            accS[k] += p[k];
        }
    }

    // fold subgroup pairs within each wave (fixed order -> deterministic)
#pragma unroll
    for (int k = 0; k < KP; ++k) {
        accM[k] += __shfl_xor(accM[k], 32);
        accS[k] += __shfl_xor(accS[k], 32);
    }
    __shared__ float red[8][MOM];
    const int wv = t >> 6;
    if ((t & 32) == 0) {
#pragma unroll
        for (int k = 0; k < KP; ++k) red[wv][KP + k * EMB + e] = accM[k];
        if (e == 0) {
#pragma unroll
            for (int k = 0; k < KP; ++k) red[wv][k] = accS[k];
        }
    }
    __syncthreads();
    for (int i = t; i < MOM; i += 512) {
        float s = 0.f;
#pragma unroll
        for (int u = 0; u < 8; ++u) s += red[u][i];
        part[((size_t)b * MOM + i) * NBLK + blk] = s;
    }
}

// ---------------- kernel 2: reduce + x(Horner) -> conv1+relu -> conv2+res+relu ----------------
// Weights/biases via wave-uniform scalar loads from ORIGINAL layout (no transpose, no LDS).
__global__ __launch_bounds__(THR) void main_kernel(
    const float* __restrict__ inten, const float* __restrict__ part,
    const float* __restrict__ w1, const float* __restrict__ b1,
    const float* __restrict__ w2, const float* __restrict__ b2,
    float* __restrict__ out)
{
    __shared__ float moms[MOM];
    __shared__ float xs[EMB][STR];  // x idx 0..136 (pos = start-2+idx)
    __shared__ float hs[EMB][STR];  // h idx j stored at [j-1], j in 1..135

    const int t = threadIdx.x;
    const int b = blockIdx.x >> 6;      // NT = 64
    const int tile = blockIdx.x & 63;
    const int start = tile * TOUT;
    const int e = t & 31;

    // ---- preload this thread's x-gen inputs (u<0 == invalid sentinel) ----
    float uu[8];
#pragma unroll
    for (int q = 0; q < 8; ++q) {
        const int i = t + q * THR;
        float u = -1.0f;
        if (i < STG * EMB) {
            const int pos = i >> 5;
            const int gp = start - 2 + pos;
            if (gp >= 0 && gp < NPOS) u = inten[b * NPOS + gp] * 0.01f;
        }
        uu[q] = u;
    }

    // ---- reduce this batch's partials: one coeff per thread, 16 x float4, 4-way ILP ----
    if (t < MOM) {
        const float4* pr = (const float4*)&part[((size_t)b * MOM + t) * NBLK];
        float4 a0 = pr[0], a1 = pr[1], a2 = pr[2], a3 = pr[3];
#pragma unroll
        for (int u = 4; u < 16; u += 4) {
            const float4 v0 = pr[u], v1 = pr[u + 1], v2 = pr[u + 2], v3 = pr[u + 3];
            a0.x += v0.x; a0.y += v0.y; a0.z += v0.z; a0.w += v0.w;
            a1.x += v1.x; a1.y += v1.y; a1.z += v1.z; a1.w += v1.w;
            a2.x += v2.x; a2.y += v2.y; a2.z += v2.z; a2.w += v2.w;
            a3.x += v3.x; a3.y += v3.y; a3.z += v3.z; a3.w += v3.w;
        }
        const float s = ((a0.x + a0.y) + (a0.z + a0.w)) + ((a1.x + a1.y) + (a1.z + a1.w))
                      + ((a2.x + a2.y) + (a2.z + a2.w)) + ((a3.x + a3.y) + (a3.z + a3.w));
        const int k = (t < KP) ? t : ((t - KP) >> 5);
        moms[t] = s * c_invf[k];
    }
    __syncthreads();

    // per-thread Horner coefficients (pre-scaled by 1/k!)
    float Mreg[KP], Sreg[KP];
#pragma unroll
    for (int k = 0; k < KP; ++k) {
        Mreg[k] = moms[KP + k * EMB + e];
        Sreg[k] = moms[k];
    }

    // ---- x-gen from preloaded u ----
#pragma unroll
    for (int q = 0; q < 8; ++q) {
        const int i = t + q * THR;
        if (i < STG * EMB) {
            const int pos = i >> 5;
            const float u = uu[q];
            const bool valid = (u >= 0.f);
            const float uc = valid ? u : 0.f;
            float num = Mreg[KP - 1], den = Sreg[KP - 1];
#pragma unroll
            for (int k = KP - 2; k >= 0; --k) {
                num = fmaf(num, uc, Mreg[k]);
                den = fmaf(den, uc, Sreg[k]);
            }
            const float rd = valid ? __builtin_amdgcn_rcpf(den) : 0.f;
            xs[e][pos] = num * rd;
        }
    }
    __syncthreads();

    const int wv = t >> 6;       // wave id 0..8
    const int lane = t & 63;

    // ---- conv1 + relu -> hs ----
    if (wv < 8) {
        const int o0 = __builtin_amdgcn_readfirstlane(wv << 2);
        const int i0 = 2 * lane;             // h idx i0+1, i0+2 (1..128)
        const float* W = w1 + o0 * 96;       // rows o0..o0+3, [o][c*3+d]
        float a[4][2];
#pragma unroll
        for (int oo = 0; oo < 4; ++oo) { const float bv = b1[o0 + oo]; a[oo][0] = bv; a[oo][1] = bv; }
#pragma unroll 4
        for (int c = 0; c < 32; ++c) {
            const float2 xa = *(const float2*)&xs[c][i0];
            const float2 xb = *(const float2*)&xs[c][i0 + 2];
#pragma unroll
            for (int oo = 0; oo < 4; ++oo) {
                const float wA = W[oo * 96 + c * 3 + 0];   // SGPR-uniform
                const float wB = W[oo * 96 + c * 3 + 1];
                const float wC = W[oo * 96 + c * 3 + 2];
                a[oo][0] = fmaf(wA, xa.x, fmaf(wB, xa.y, fmaf(wC, xb.x, a[oo][0])));
                a[oo][1] = fmaf(wA, xa.y, fmaf(wB, xb.x, fmaf(wC, xb.y, a[oo][1])));
            }
        }
        const int gp0 = start - 1 + i0;      // pos of h idx i0+1
        const bool v0 = (gp0 >= 0) && (gp0 < NPOS);
        const bool v1 = (gp0 + 1 >= 0) && (gp0 + 1 < NPOS);
#pragma unroll
        for (int oo = 0; oo < 4; ++oo) {
            float2 hv;
            hv.x = v0 ? fmaxf(a[oo][0], 0.f) : 0.f;
            hv.y = v1 ? fmaxf(a[oo][1], 0.f) : 0.f;
            *(float2*)&hs[o0 + oo][i0] = hv;
        }
    } else {
        // edge wave: h idx 129..135 for all 8 channel groups
        const int g2 = lane >> 3, p = lane & 7;
        if (p < 7) {
            const int o0e = g2 << 2;
            const int j = 129 + p;           // h idx
            float a[4];
#pragma unroll
            for (int oo = 0; oo < 4; ++oo) a[oo] = b1[o0e + oo];
#pragma unroll 4
            for (int c = 0; c < 32; ++c) {
                const float x0 = xs[c][j - 1], x1 = xs[c][j], x2 = xs[c][j + 1];
#pragma unroll
                for (int oo = 0; oo < 4; ++oo) {
                    const float wa = w1[(o0e + oo) * 96 + c * 3 + 0];
                    const float wb = w1[(o0e + oo) * 96 + c * 3 + 1];
                    const float wc = w1[(o0e + oo) * 96 + c * 3 + 2];
                    a[oo] = fmaf(wa, x0, fmaf(wb, x1, fmaf(wc, x2, a[oo])));
                }
            }
            const int gp = start - 2 + j;    // >= 127, only upper clamp needed
            const bool v = gp < NPOS;
#pragma unroll
            for (int oo = 0; oo < 4; ++oo)
                hs[o0e + oo][j - 1] = v ? fmaxf(a[oo], 0.f) : 0.f;
        }
    }
    __syncthreads();

    // ---- conv2 + residual + relu -> out ----
    if (wv < 8) {
        const int o0 = __builtin_amdgcn_readfirstlane(wv << 2);
        const int i0 = 2 * lane;             // out idx i0+2, i0+3 (2..129)
        const float* W = w2 + o0 * 96;
        float a[4][2];
#pragma unroll
        for (int oo = 0; oo < 4; ++oo) { const float bv = b2[o0 + oo]; a[oo][0] = bv; a[oo][1] = bv; }
#pragma unroll 4
        for (int c = 0; c < 32; ++c) {
            const float2 ha = *(const float2*)&hs[c][i0];
            const float2 hb = *(const float2*)&hs[c][i0 + 2];
#pragma unroll
            for (int oo = 0; oo < 4; ++oo) {
                const float wA = W[oo * 96 + c * 3 + 0];
                const float wB = W[oo * 96 + c * 3 + 1];
                const float wC = W[oo * 96 + c * 3 + 2];
                a[oo][0] = fmaf(wA, ha.x, fmaf(wB, ha.y, fmaf(wC, hb.x, a[oo][0])));
                a[oo][1] = fmaf(wA, ha.y, fmaf(wB, hb.x, fmaf(wC, hb.y, a[oo][1])));
            }
        }
        const int p0 = start + i0;           // pos of out idx i0+2
        if (p0 < NPOS) {
            const bool full = (p0 + 1 < NPOS);
#pragma unroll
            for (int oo = 0; oo < 4; ++oo) {
                const float2 xr = *(const float2*)&xs[o0 + oo][i0 + 2];
                const float r0 = fmaxf(xr.x + a[oo][0], 0.f);
                const float r1 = fmaxf(xr.y + a[oo][1], 0.f);
                float* ob = out + (size_t)(b * EMB + o0 + oo) * NPOS + p0;
                if (full) *(float2*)ob = make_float2(r0, r1);
                else ob[0] = r0;
            }
        }
    } else {
        // edge wave: out idx 130..134 for all 8 channel groups
        const int g2 = lane >> 3, p = lane & 7;
        if (p < 5) {
            const int o0e = g2 << 2;
            const int q = 130 + p;           // out idx; h taps stored at [q-2],[q-1],[q]
            float a[4];
#pragma unroll
            for (int oo = 0; oo < 4; ++oo) a[oo] = b2[o0e + oo];
#pragma unroll 4
            for (int c = 0; c < 32; ++c) {
                const float h0 = hs[c][q - 2], h1 = hs[c][q - 1], h2 = hs[c][q];
#pragma unroll
                for (int oo = 0; oo < 4; ++oo) {
                    const float wa = w2[(o0e + oo) * 96 + c * 3 + 0];
                    const float wb = w2[(o0e + oo) * 96 + c * 3 + 1];
                    const float wc = w2[(o0e + oo) * 96 + c * 3 + 2];
                    a[oo] = fmaf(wa, h0, fmaf(wb, h1, fmaf(wc, h2, a[oo])));
                }
            }
            const int pos = start + q - 2;   // start+128+p
            if (pos < NPOS) {
#pragma unroll
                for (int oo = 0; oo < 4; ++oo) {
                    const float r = fmaxf(xs[o0e + oo][q] + a[oo], 0.f);
                    out[(size_t)(b * EMB + o0e + oo) * NPOS + pos] = r;
                }
            }
        }
    }
}

extern "C" void kernel_launch(void* const* d_in, const int* in_sizes, int n_in,
                              void* d_out, int out_size, void* d_ws, size_t ws_size,
                              hipStream_t stream) {
    const float* inten = (const float*)d_in[0];
    const int* angle = (const int*)d_in[1];
    const float* emb = (const float*)d_in[2];
    const float* w1 = (const float*)d_in[3];
    const float* b1 = (const float*)d_in[4];
    const float* w2 = (const float*)d_in[5];
    const float* b2 = (const float*)d_in[6];
    float* out = (float*)d_out;

    float* part = (float*)d_ws;   // BB*528*64*4 = 540672 B

    moments_partial<<<BB * NBLK, 512, 0, stream>>>(inten, angle, emb, part);
    main_kernel<<<BB * NT, THR, 0, stream>>>(inten, part, w1, b1, w2, b2, out);
}